// Round 1
// 401.915 us; speedup vs baseline: 1.0348x; 1.0348x over previous
//
#include <hip/hip_runtime.h>

// S=4096, B=8, D=1024, BN=128; M = S*B = 32768 rows. fp32 I/O, bf16 MFMA inside.
#define S_DIM 4096
#define B_DIM 8
#define D_DIM 1024
#define BN_DIM 128
#define M_DIM (S_DIM * B_DIM)
#define LDK 72    // K2 LDS row stride (ushorts): 36 dwords ≡ 4 mod 32 -> 2-way (free)
#define LDK3 136  // K3 LDS row stride (ushorts): 68 dwords ≡ 4 mod 32 -> 2-way (free)
#define CLD 132   // K3 epilogue transpose stride (floats)

typedef short s8v __attribute__((ext_vector_type(8)));
typedef float f4v __attribute__((ext_vector_type(4)));

__device__ __forceinline__ unsigned short f2bf(float f) {
  union { unsigned int i; float f; } v; v.f = f;
  unsigned int r = v.i + 0x7FFFu + ((v.i >> 16) & 1u);
  return (unsigned short)(r >> 16);
}
__device__ __forceinline__ float bf2f(unsigned short u) {
  union { unsigned int i; float f; } v; v.i = ((unsigned int)u) << 16; return v.f;
}

// ---------------------------------------------------------------------------
// Prep: Wd'[n,k] = W_down[n,k]*gamma[k] (bf16); bd'[n] = b_down[n] + W_down[n,:]·beta;
//       Wu' = bf16(W_up). Blocks 0..127: row n of W_down. Blocks 128..159: W_up chunks.
// ---------------------------------------------------------------------------
__global__ __launch_bounds__(256) void prep_kernel(
    const float* __restrict__ Wd_f, const float* __restrict__ bd_f,
    const float* __restrict__ Wu_f, const float* __restrict__ gamma,
    const float* __restrict__ beta,
    unsigned short* __restrict__ Wd, float* __restrict__ bd,
    unsigned short* __restrict__ Wu) {
  __shared__ float red[4];
  int t = threadIdx.x;
  if (blockIdx.x < 128) {
    int n = blockIdx.x, k = t * 4;
    float4 w = *(const float4*)&Wd_f[n * 1024 + k];
    float4 g = *(const float4*)&gamma[k];
    float4 bt = *(const float4*)&beta[k];
    ushort4 o;
    o.x = f2bf(w.x * g.x); o.y = f2bf(w.y * g.y);
    o.z = f2bf(w.z * g.z); o.w = f2bf(w.w * g.w);
    *(ushort4*)&Wd[n * 1024 + k] = o;
    float bs = w.x * bt.x + w.y * bt.y + w.z * bt.z + w.w * bt.w;
#pragma unroll
    for (int ofs = 32; ofs >= 1; ofs >>= 1) bs += __shfl_xor(bs, ofs, 64);
    if ((t & 63) == 0) red[t >> 6] = bs;
    __syncthreads();
    if (t == 0) bd[n] = bd_f[n] + red[0] + red[1] + red[2] + red[3];
  } else {
    int j = blockIdx.x - 128;
#pragma unroll
    for (int c = 0; c < 4; ++c) {
      int idx = j * 4096 + c * 1024 + t * 4;
      float4 w = *(const float4*)&Wu_f[idx];
      ushort4 o;
      o.x = f2bf(w.x); o.y = f2bf(w.y); o.z = f2bf(w.z); o.w = f2bf(w.w);
      *(ushort4*)&Wu[idx] = o;
    }
    __syncthreads();  // keep barrier count uniform
  }
}

// ---------------------------------------------------------------------------
// K1: y = x + res^T -> bf16 ws; stats (mu, rstd) per row.
// One row per WAVE, grid-stride. No LDS, no block sync, ~48 VGPR -> 8 waves/SIMD.
// Latency model: 32 waves/CU x 8 outstanding 16B loads ~ 8 KB in flight/CU
// -> ~9 B/cyc/CU -> ~5 TB/s (vs 1.7 measured with the old serialized 2-row tile).
// ---------------------------------------------------------------------------
__global__ __launch_bounds__(256) void add_ln_kernel(
    const float* __restrict__ x, const float* __restrict__ res,
    unsigned short* __restrict__ y, float2* __restrict__ stats) {
  int wave = threadIdx.x >> 6, lane = threadIdx.x & 63;
  for (int row = blockIdx.x * 4 + wave; row < M_DIM; row += gridDim.x * 4) {
    const float* xr = x + (size_t)row * D_DIM;
    const float* rr = res + ((size_t)(row & 7) * S_DIM + (row >> 3)) * D_DIM;
    float4 xa[4], ra[4];
#pragma unroll
    for (int c = 0; c < 4; ++c) xa[c] = *(const float4*)&xr[c * 256 + lane * 4];
#pragma unroll
    for (int c = 0; c < 4; ++c) ra[c] = *(const float4*)&rr[c * 256 + lane * 4];
    float sum = 0.f, sq = 0.f;
#pragma unroll
    for (int c = 0; c < 4; ++c) {
      xa[c].x += ra[c].x; xa[c].y += ra[c].y;
      xa[c].z += ra[c].z; xa[c].w += ra[c].w;
      sum += xa[c].x + xa[c].y + xa[c].z + xa[c].w;
      sq += xa[c].x * xa[c].x + xa[c].y * xa[c].y +
            xa[c].z * xa[c].z + xa[c].w * xa[c].w;
    }
#pragma unroll
    for (int ofs = 32; ofs >= 1; ofs >>= 1) {
      sum += __shfl_xor(sum, ofs, 64);
      sq  += __shfl_xor(sq, ofs, 64);
    }
    float mu = sum * (1.f / D_DIM);
    float var = sq * (1.f / D_DIM) - mu * mu;
    float rstd = rsqrtf(var + 1e-5f);
    if (lane == 0) stats[row] = make_float2(mu, rstd);
    unsigned short* yr = y + (size_t)row * D_DIM;
#pragma unroll
    for (int c = 0; c < 4; ++c) {
      ushort4 o;
      o.x = f2bf(xa[c].x); o.y = f2bf(xa[c].y);
      o.z = f2bf(xa[c].z); o.w = f2bf(xa[c].w);
      *(ushort4*)&yr[c * 256 + lane * 4] = o;
    }
  }
}

// ---------------------------------------------------------------------------
// K2: H = relu(norm(y) @ Wd'^T + bd')  [M,128]; normalize during A staging.
// Tile M=64, N=128, K-step 64 (16 steps). Double-buffered LDS, reg-staged
// prefetch issued AFTER the barrier (in flight during MFMA). ONE barrier/step
// (double buffer makes the read/write phases hazard-free). Wave-grid 2Mx2N.
// ---------------------------------------------------------------------------
__global__ __launch_bounds__(256) void gemm_down(
    const unsigned short* __restrict__ Y,    // [M,1024] bf16
    const unsigned short* __restrict__ Wd,   // [128,1024] bf16 (gamma folded)
    const float* __restrict__ bd,            // [128] fp32 (beta folded)
    const float2* __restrict__ stats,        // [M] (mu, rstd)
    unsigned short* __restrict__ H) {        // [M,128] bf16
  __shared__ unsigned short sm[2 * (64 * LDK + 128 * LDK)];  // 2 x 27.6 KB
  int t = threadIdx.x, wid = t >> 6, lane = t & 63;
  int tileM = blockIdx.x * 64;
  // A staging: thread t -> row t>>2, 2 chunks at (t&3)*16 + {0,8}
  int arow = t >> 2, ac0 = (t & 3) * 16;
  float2 st = stats[tileM + arow];
  float rstd = st.y, nmu = -st.x * st.y;
  const unsigned short* Yr = Y + (size_t)(tileM + arow) * D_DIM + ac0;
  // B staging: thread t -> row t>>1, 4 chunks at (t&1)*32 + {0,8,16,24}
  int brow = t >> 1, bc0 = (t & 1) * 32;
  const unsigned short* Wr = Wd + (size_t)brow * D_DIM + bc0;

  f4v acc[2][4];
#pragma unroll
  for (int am = 0; am < 2; ++am)
#pragma unroll
    for (int nt = 0; nt < 4; ++nt) acc[am][nt] = (f4v){0.f, 0.f, 0.f, 0.f};

  s8v aR0 = *(const s8v*)&Yr[0], aR1 = *(const s8v*)&Yr[8];
  s8v bR0 = *(const s8v*)&Wr[0], bR1 = *(const s8v*)&Wr[8];
  s8v bR2 = *(const s8v*)&Wr[16], bR3 = *(const s8v*)&Wr[24];

  int wm = wid & 1, wn = wid >> 1;
  int kq = (lane >> 4) * 8, fr = lane & 15;
  int aoff = arow * LDK + ac0;
  int boff = 64 * LDK + brow * LDK + bc0;

#pragma unroll 2
  for (int step = 0; step < 16; ++step) {
    unsigned short* buf = sm + (step & 1) * (64 * LDK + 128 * LDK);
    // normalize + stage current regs -> LDS
    s8v av0, av1;
#pragma unroll
    for (int j = 0; j < 8; ++j) {
      av0[j] = (short)f2bf(bf2f((unsigned short)aR0[j]) * rstd + nmu);
      av1[j] = (short)f2bf(bf2f((unsigned short)aR1[j]) * rstd + nmu);
    }
    *(s8v*)&buf[aoff] = av0;      *(s8v*)&buf[aoff + 8] = av1;
    *(s8v*)&buf[boff] = bR0;      *(s8v*)&buf[boff + 8] = bR1;
    *(s8v*)&buf[boff + 16] = bR2; *(s8v*)&buf[boff + 24] = bR3;
    __syncthreads();
    // prefetch next K-slab (in flight during MFMA below)
    if (step < 15) {
      int kk = (step + 1) * 64;
      aR0 = *(const s8v*)&Yr[kk];      aR1 = *(const s8v*)&Yr[kk + 8];
      bR0 = *(const s8v*)&Wr[kk];      bR1 = *(const s8v*)&Wr[kk + 8];
      bR2 = *(const s8v*)&Wr[kk + 16]; bR3 = *(const s8v*)&Wr[kk + 24];
    }
    const unsigned short* As = buf;
    const unsigned short* Bs = buf + 64 * LDK;
    s8v a[2][2], b[4][2];
#pragma unroll
    for (int am = 0; am < 2; ++am) {
      const unsigned short* p = &As[(wm * 32 + am * 16 + fr) * LDK + kq];
      a[am][0] = *(const s8v*)&p[0];
      a[am][1] = *(const s8v*)&p[32];
    }
#pragma unroll
    for (int nt = 0; nt < 4; ++nt) {
      const unsigned short* p = &Bs[(wn * 64 + nt * 16 + fr) * LDK + kq];
      b[nt][0] = *(const s8v*)&p[0];
      b[nt][1] = *(const s8v*)&p[32];
    }
#pragma unroll
    for (int am = 0; am < 2; ++am)
#pragma unroll
      for (int nt = 0; nt < 4; ++nt) {
        acc[am][nt] = __builtin_amdgcn_mfma_f32_16x16x32_bf16(a[am][0], b[nt][0], acc[am][nt], 0, 0, 0);
        acc[am][nt] = __builtin_amdgcn_mfma_f32_16x16x32_bf16(a[am][1], b[nt][1], acc[am][nt], 0, 0, 0);
      }
  }
#pragma unroll
  for (int nt = 0; nt < 4; ++nt) {
    int n = wn * 64 + nt * 16 + fr;
    float bs = bd[n];
#pragma unroll
    for (int am = 0; am < 2; ++am)
#pragma unroll
      for (int r = 0; r < 4; ++r) {
        int m = wm * 32 + am * 16 + (lane >> 4) * 4 + r;
        float val = acc[am][nt][r] + bs;
        val = val > 0.f ? val : 0.f;
        H[(size_t)(tileM + m) * BN_DIM + n] = f2bf(val);
      }
  }
}

// ---------------------------------------------------------------------------
// K3: out = H @ Wu'^T + b_up + y (bf16 shortcut). K=128 staged ONCE (deep
// 12x16B load queue, no K-loop barriers). Y/bias prefetched to regs before
// MFMA. Cs unioned into the dead As region -> LDS 52 KB, 2-pass epilogue.
// ---------------------------------------------------------------------------
__global__ __launch_bounds__(256) void gemm_up(
    const unsigned short* __restrict__ H,    // [M,128] bf16
    const unsigned short* __restrict__ Wu,   // [1024,128] bf16
    const float* __restrict__ bias,          // [1024] fp32
    const unsigned short* __restrict__ Y,    // [M,1024] bf16 shortcut
    float* __restrict__ out) {               // [M,1024] fp32
  __shared__ __align__(16) unsigned char smraw[(64 + 128) * LDK3 * 2];  // 52224 B
  unsigned short* As = (unsigned short*)smraw;      // [64][LDK3]
  unsigned short* Bs = As + 64 * LDK3;              // [128][LDK3]
  float* Cs = (float*)smraw;                        // [32][CLD], union w/ dead As
  int t = threadIdx.x, wid = t >> 6, lane = t & 63;
  int tileM = blockIdx.x * 64, tileN = blockIdx.y * BN_DIM;

  // stage A (H tile, 64x128) : 1024 16B chunks
#pragma unroll
  for (int i = 0; i < 4; ++i) {
    int ch = i * 256 + t, r = ch >> 4, c = (ch & 15) * 8;
    *(s8v*)&As[r * LDK3 + c] = *(const s8v*)&H[(size_t)(tileM + r) * BN_DIM + c];
  }
  // stage B (Wu tile, 128x128) : 2048 16B chunks
#pragma unroll
  for (int i = 0; i < 8; ++i) {
    int ch = i * 256 + t, r = ch >> 4, c = (ch & 15) * 8;
    *(s8v*)&Bs[r * LDK3 + c] = *(const s8v*)&Wu[(size_t)(tileN + r) * BN_DIM + c];
  }
  // prefetch epilogue operands (hide HBM latency under staging wait + MFMA)
  int erow = t >> 4, ecol = (t & 15) * 8;
  s8v yv[4];
#pragma unroll
  for (int p = 0; p < 4; ++p)
    yv[p] = *(const s8v*)&Y[(size_t)(tileM + p * 16 + erow) * D_DIM + tileN + ecol];
  float4 bv0 = *(const float4*)&bias[tileN + ecol];
  float4 bv1 = *(const float4*)&bias[tileN + ecol + 4];
  __syncthreads();

  int wm = wid & 1, wn = wid >> 1, kq = (lane >> 4) * 8, fr = lane & 15;
  f4v acc[2][4];
#pragma unroll
  for (int am = 0; am < 2; ++am)
#pragma unroll
    for (int nt = 0; nt < 4; ++nt) acc[am][nt] = (f4v){0.f, 0.f, 0.f, 0.f};

  s8v a[2][4];
#pragma unroll
  for (int am = 0; am < 2; ++am) {
    const unsigned short* p = &As[(wm * 32 + am * 16 + fr) * LDK3 + kq];
#pragma unroll
    for (int ks = 0; ks < 4; ++ks) a[am][ks] = *(const s8v*)&p[ks * 32];
  }
#pragma unroll
  for (int nt = 0; nt < 4; ++nt) {
    const unsigned short* p = &Bs[(wn * 64 + nt * 16 + fr) * LDK3 + kq];
#pragma unroll
    for (int ks = 0; ks < 4; ++ks) {
      s8v b = *(const s8v*)&p[ks * 32];
#pragma unroll
      for (int am = 0; am < 2; ++am)
        acc[am][nt] = __builtin_amdgcn_mfma_f32_16x16x32_bf16(a[am][ks], b, acc[am][nt], 0, 0, 0);
    }
  }
  // 2-pass transpose epilogue through Cs (overwrites dead As region)
#pragma unroll
  for (int pass = 0; pass < 2; ++pass) {
    __syncthreads();  // pass0: all LDS reads done; pass1: pass0 Cs reads done
    if (wm == pass) {
#pragma unroll
      for (int nt = 0; nt < 4; ++nt) {
        int n = wn * 64 + nt * 16 + fr;
#pragma unroll
        for (int am = 0; am < 2; ++am)
#pragma unroll
          for (int r = 0; r < 4; ++r) {
            int ml = am * 16 + (lane >> 4) * 4 + r;  // 0..31 local row
            Cs[ml * CLD + n] = acc[am][nt][r];
          }
      }
    }
    __syncthreads();
#pragma unroll
    for (int s = 0; s < 2; ++s) {
      int ml = s * 16 + erow;
      size_t gbase = (size_t)(tileM + pass * 32 + ml) * D_DIM + tileN + ecol;
      const float* cs = &Cs[ml * CLD + ecol];
      s8v yq = yv[pass * 2 + s];
      float4 o0, o1;
      o0.x = cs[0] + bv0.x + bf2f((unsigned short)yq[0]);
      o0.y = cs[1] + bv0.y + bf2f((unsigned short)yq[1]);
      o0.z = cs[2] + bv0.z + bf2f((unsigned short)yq[2]);
      o0.w = cs[3] + bv0.w + bf2f((unsigned short)yq[3]);
      o1.x = cs[4] + bv1.x + bf2f((unsigned short)yq[4]);
      o1.y = cs[5] + bv1.y + bf2f((unsigned short)yq[5]);
      o1.z = cs[6] + bv1.z + bf2f((unsigned short)yq[6]);
      o1.w = cs[7] + bv1.w + bf2f((unsigned short)yq[7]);
      *(float4*)&out[gbase] = o0;
      *(float4*)&out[gbase + 4] = o1;
    }
  }
}

// ---------------------------------------------------------------------------
extern "C" void kernel_launch(void* const* d_in, const int* in_sizes, int n_in,
                              void* d_out, int out_size, void* d_ws, size_t ws_size,
                              hipStream_t stream) {
  const float* x      = (const float*)d_in[0];
  const float* res    = (const float*)d_in[1];
  const float* gamma  = (const float*)d_in[2];
  const float* beta   = (const float*)d_in[3];
  const float* W_down = (const float*)d_in[4];
  const float* b_down = (const float*)d_in[5];
  const float* W_up   = (const float*)d_in[6];
  const float* b_up   = (const float*)d_in[7];
  float* out = (float*)d_out;

  // ws layout: y [M,1024] bf16 | h1 [M,128] bf16 | stats [M] float2 |
  //            Wd' [128,1024] bf16 | bd' [128] f32 | Wu' [1024,128] bf16
  unsigned short* ws_y  = (unsigned short*)d_ws;
  unsigned short* ws_h1 = ws_y + (size_t)M_DIM * D_DIM;
  float2* ws_stats      = (float2*)(ws_h1 + (size_t)M_DIM * BN_DIM);
  unsigned short* ws_wd = (unsigned short*)(ws_stats + M_DIM);
  float* ws_bd          = (float*)(ws_wd + 128 * 1024);
  unsigned short* ws_wu = (unsigned short*)(ws_bd + 128);

  prep_kernel<<<160, 256, 0, stream>>>(W_down, b_down, W_up, gamma, beta,
                                       ws_wd, ws_bd, ws_wu);
  add_ln_kernel<<<2048, 256, 0, stream>>>(x, res, ws_y, ws_stats);
  gemm_down<<<M_DIM / 64, 256, 0, stream>>>(ws_y, ws_wd, ws_bd, ws_stats, ws_h1);
  gemm_up<<<dim3(M_DIM / 64, D_DIM / 128), 256, 0, stream>>>(ws_h1, ws_wu, b_up,
                                                             ws_y, out);
}